// Round 1
// baseline (150.998 us; speedup 1.0000x reference)
//
#include <hip/hip_runtime.h>
#include <math.h>

#define LAG 100
#define HID 150
#define G4  (4*HID)   // 600 gate rows per layer

__device__ __forceinline__ float sigmoidf_(float x) {
    return 1.0f / (1.0f + expf(-x));
}

// One fused kernel: layer0 gates -> (h1,c1) -> layer1 gates -> (h2,c2) -> linear.
// Single workgroup of 640 threads (10 waves); LDS staging between stages.
extern "C" __global__ __launch_bounds__(640, 1)
void lstm_step_kernel(const float* __restrict__ x,     // [100]
                      const float* __restrict__ h0,    // [2,150]
                      const float* __restrict__ c0,    // [2,150]
                      const float* __restrict__ Wih0,  // [600,100]
                      const float* __restrict__ Whh0,  // [600,150]
                      const float* __restrict__ bih0,  // [600]
                      const float* __restrict__ bhh0,  // [600]
                      const float* __restrict__ Wih1,  // [600,150]
                      const float* __restrict__ Whh1,  // [600,150]
                      const float* __restrict__ bih1,  // [600]
                      const float* __restrict__ bhh1,  // [600]
                      const float* __restrict__ Wlin,  // [150]
                      const float* __restrict__ blin,  // [1]
                      float* __restrict__ out)         // [1]
{
    __shared__ float sx[LAG];    // layer0 input
    __shared__ float sh[HID];    // h_prev for current layer
    __shared__ float sg[G4];     // gates
    __shared__ float sh1[HID];   // h output of a layer / linear partials

    const int t = threadIdx.x;

    // Stage 0: load x and h0[layer0] into LDS
    if (t < LAG) sx[t] = x[t];
    if (t < HID) sh[t] = h0[t];
    __syncthreads();

    // Stage 1: layer0 gates. Row t: 100-dot with x (float4) + 150-dot with h (float2)
    if (t < G4) {
        float acc = bih0[t] + bhh0[t];
        const float4* w4 = (const float4*)(Wih0 + t * LAG);   // 400B rows, 16B aligned
        for (int k = 0; k < LAG / 4; ++k) {
            float4 w = w4[k];
            acc = fmaf(w.x, sx[4*k+0], acc);
            acc = fmaf(w.y, sx[4*k+1], acc);
            acc = fmaf(w.z, sx[4*k+2], acc);
            acc = fmaf(w.w, sx[4*k+3], acc);
        }
        const float2* w2 = (const float2*)(Whh0 + t * HID);   // 600B rows, 8B aligned
        for (int k = 0; k < HID / 2; ++k) {
            float2 w = w2[k];
            acc = fmaf(w.x, sh[2*k+0], acc);
            acc = fmaf(w.y, sh[2*k+1], acc);
        }
        sg[t] = acc;
    }
    __syncthreads();

    // Stage 2: layer0 cell update -> h1 in LDS; also stage h0[layer1]
    if (t < HID) {
        float i = sigmoidf_(sg[t]);
        float f = sigmoidf_(sg[HID + t]);
        float g = tanhf(sg[2*HID + t]);
        float o = sigmoidf_(sg[3*HID + t]);
        float c = fmaf(f, c0[t], i * g);
        sh1[t] = o * tanhf(c);
        sh[t]  = h0[HID + t];   // safe: all stage-1 reads of sh[] are before prior barrier
    }
    __syncthreads();

    // Stage 3: layer1 gates. Row t: 150-dot with h1 + 150-dot with h0[1]
    if (t < G4) {
        float acc = bih1[t] + bhh1[t];
        const float2* wi = (const float2*)(Wih1 + t * HID);
        const float2* wh = (const float2*)(Whh1 + t * HID);
        for (int k = 0; k < HID / 2; ++k) {
            float2 a = wi[k];
            float2 b = wh[k];
            acc = fmaf(a.x, sh1[2*k+0], acc);
            acc = fmaf(a.y, sh1[2*k+1], acc);
            acc = fmaf(b.x, sh[2*k+0], acc);
            acc = fmaf(b.y, sh[2*k+1], acc);
        }
        sg[t] = acc;
    }
    __syncthreads();

    // Stage 4: layer1 cell update -> h2, fused with W_lin elementwise product
    if (t < HID) {
        float i = sigmoidf_(sg[t]);
        float f = sigmoidf_(sg[HID + t]);
        float g = tanhf(sg[2*HID + t]);
        float o = sigmoidf_(sg[3*HID + t]);
        float c = fmaf(f, c0[HID + t], i * g);
        float h2 = o * tanhf(c);
        sh1[t] = h2 * Wlin[t];
    }
    __syncthreads();

    // Stage 5: reduce 150 partials in wave 0 (full 64 lanes active), add bias
    if (t < 64) {
        float s = sh1[t];
        if (t + 64  < HID) s += sh1[t + 64];
        if (t + 128 < HID) s += sh1[t + 128];
        for (int off = 32; off > 0; off >>= 1)
            s += __shfl_down(s, off, 64);
        if (t == 0) out[0] = s + blin[0];
    }
}

extern "C" void kernel_launch(void* const* d_in, const int* in_sizes, int n_in,
                              void* d_out, int out_size, void* d_ws, size_t ws_size,
                              hipStream_t stream) {
    const float* x    = (const float*)d_in[0];
    const float* h0   = (const float*)d_in[1];
    const float* c0   = (const float*)d_in[2];
    const float* Wih0 = (const float*)d_in[3];
    const float* Whh0 = (const float*)d_in[4];
    const float* bih0 = (const float*)d_in[5];
    const float* bhh0 = (const float*)d_in[6];
    const float* Wih1 = (const float*)d_in[7];
    const float* Whh1 = (const float*)d_in[8];
    const float* bih1 = (const float*)d_in[9];
    const float* bhh1 = (const float*)d_in[10];
    const float* Wlin = (const float*)d_in[11];
    const float* blin = (const float*)d_in[12];
    float* out = (float*)d_out;

    lstm_step_kernel<<<1, 640, 0, stream>>>(x, h0, c0,
                                            Wih0, Whh0, bih0, bhh0,
                                            Wih1, Whh1, bih1, bhh1,
                                            Wlin, blin, out);
}

// Round 2
// 83.719 us; speedup vs baseline: 1.8036x; 1.8036x over previous
//
#include <hip/hip_runtime.h>
#include <math.h>

#define LAG 100
#define HID 150
#define G4  (4*HID)   // 600 gate rows per layer

__device__ __forceinline__ float sigmoidf_(float x) {
    return 1.0f / (1.0f + expf(-x));
}

// ---------------- K1: layer0 gates ----------------
// 150 blocks x 256 threads = 600 waves; wave w computes gate row w.
// Row dot (len 100 + len 150) split across 64 lanes (coalesced), shuffle-reduced.
extern "C" __global__ __launch_bounds__(256, 1)
void k_gates0(const float* __restrict__ x,     // [100]
              const float* __restrict__ h0,    // [2,150]
              const float* __restrict__ Wih0,  // [600,100]
              const float* __restrict__ Whh0,  // [600,150]
              const float* __restrict__ bih0,  // [600]
              const float* __restrict__ bhh0,  // [600]
              float* __restrict__ sg0)         // [600] out (ws)
{
    __shared__ float sv[LAG + HID];            // x ++ h0[layer0]
    const int t = threadIdx.x;
    if (t < LAG)            sv[t] = x[t];
    else if (t < LAG + HID) sv[t] = h0[t - LAG];
    __syncthreads();

    const int r    = (blockIdx.x << 2) + (t >> 6);   // 0..599
    const int lane = t & 63;

    float acc = 0.0f;
    const float* __restrict__ wi = Wih0 + r * LAG;
    for (int k = lane; k < LAG; k += 64)
        acc = fmaf(wi[k], sv[k], acc);
    const float* __restrict__ wh = Whh0 + r * HID;
    for (int k = lane; k < HID; k += 64)
        acc = fmaf(wh[k], sv[LAG + k], acc);

    for (int off = 32; off > 0; off >>= 1)
        acc += __shfl_down(acc, off, 64);
    if (lane == 0)
        sg0[r] = acc + bih0[r] + bhh0[r];
}

// ---------------- K2: cell0 (redundant per block) + layer1 gates ----------------
extern "C" __global__ __launch_bounds__(256, 1)
void k_cell0_gates1(const float* __restrict__ sg0,   // [600] (ws)
                    const float* __restrict__ c0,    // [2,150]
                    const float* __restrict__ h0,    // [2,150]
                    const float* __restrict__ Wih1,  // [600,150]
                    const float* __restrict__ Whh1,  // [600,150]
                    const float* __restrict__ bih1,  // [600]
                    const float* __restrict__ bhh1,  // [600]
                    float* __restrict__ sg1)         // [600] out (ws)
{
    __shared__ float sh1[HID];    // h1 = layer0 output
    __shared__ float sh01[HID];   // h0[layer1]
    const int t = threadIdx.x;
    if (t < HID) {
        float i = sigmoidf_(sg0[t]);
        float f = sigmoidf_(sg0[HID + t]);
        float g = tanhf(sg0[2 * HID + t]);
        float o = sigmoidf_(sg0[3 * HID + t]);
        float c = fmaf(f, c0[t], i * g);
        sh1[t]  = o * tanhf(c);
        sh01[t] = h0[HID + t];
    }
    __syncthreads();

    const int r    = (blockIdx.x << 2) + (t >> 6);   // 0..599
    const int lane = t & 63;

    float acc = 0.0f;
    const float* __restrict__ wi = Wih1 + r * HID;
    const float* __restrict__ wh = Whh1 + r * HID;
    for (int k = lane; k < HID; k += 64) {
        acc = fmaf(wi[k], sh1[k], acc);
        acc = fmaf(wh[k], sh01[k], acc);
    }

    for (int off = 32; off > 0; off >>= 1)
        acc += __shfl_down(acc, off, 64);
    if (lane == 0)
        sg1[r] = acc + bih1[r] + bhh1[r];
}

// ---------------- K3: cell1 + linear ----------------
extern "C" __global__ __launch_bounds__(256, 1)
void k_cell1_out(const float* __restrict__ sg1,   // [600] (ws)
                 const float* __restrict__ c0,    // [2,150]
                 const float* __restrict__ Wlin,  // [150]
                 const float* __restrict__ blin,  // [1]
                 float* __restrict__ out)         // [1]
{
    const int t = threadIdx.x;
    float v = 0.0f;
    if (t < HID) {
        float i = sigmoidf_(sg1[t]);
        float f = sigmoidf_(sg1[HID + t]);
        float g = tanhf(sg1[2 * HID + t]);
        float o = sigmoidf_(sg1[3 * HID + t]);
        float c = fmaf(f, c0[HID + t], i * g);
        v = o * tanhf(c) * Wlin[t];
    }
    for (int off = 32; off > 0; off >>= 1)
        v += __shfl_down(v, off, 64);

    __shared__ float wsum[4];
    if ((t & 63) == 0) wsum[t >> 6] = v;
    __syncthreads();
    if (t == 0)
        out[0] = wsum[0] + wsum[1] + wsum[2] + wsum[3] + blin[0];
}

extern "C" void kernel_launch(void* const* d_in, const int* in_sizes, int n_in,
                              void* d_out, int out_size, void* d_ws, size_t ws_size,
                              hipStream_t stream) {
    const float* x    = (const float*)d_in[0];
    const float* h0   = (const float*)d_in[1];
    const float* c0   = (const float*)d_in[2];
    const float* Wih0 = (const float*)d_in[3];
    const float* Whh0 = (const float*)d_in[4];
    const float* bih0 = (const float*)d_in[5];
    const float* bhh0 = (const float*)d_in[6];
    const float* Wih1 = (const float*)d_in[7];
    const float* Whh1 = (const float*)d_in[8];
    const float* bih1 = (const float*)d_in[9];
    const float* bhh1 = (const float*)d_in[10];
    const float* Wlin = (const float*)d_in[11];
    const float* blin = (const float*)d_in[12];
    float* out = (float*)d_out;

    float* sg0 = (float*)d_ws;          // [600]
    float* sg1 = sg0 + G4;              // [600]

    k_gates0<<<150, 256, 0, stream>>>(x, h0, Wih0, Whh0, bih0, bhh0, sg0);
    k_cell0_gates1<<<150, 256, 0, stream>>>(sg0, c0, h0, Wih1, Whh1, bih1, bhh1, sg1);
    k_cell1_out<<<1, 256, 0, stream>>>(sg1, c0, Wlin, blin, out);
}